// Round 8
// baseline (718.633 us; speedup 1.0000x reference)
//
#include <hip/hip_runtime.h>
#include <hip/hip_fp16.h>

// ---------------------------------------------------------------------------
// VariationalGCNEncoder: mu/logstd = GCNConv(relu(GCNConv(x)))
// N=100000, E=1600000, IN=256, HID=128, OUT=64
//
// R8: channel-sharded gather. H stored as 8 group arrays [g][node][16ch]
//     (3.2 MB each -- fits one XCD's 4MB L2). agg grid: group = bid&7, so
//     round-robin XCD dispatch pins each group to one XCD => random row
//     gathers become L2-resident. cw read nontemporally (no L2 thrash).
//     Stored-channel semantics unchanged; only addr(node,s) changed to
//     (s>>4)*N*16 + node*16 + (s&15).
// Pipeline: bhist->bscan->bpart->bfin | prep_all | gemm1 -> agg_g<1>
//           -> agg_g<0> -> gemm2
// ---------------------------------------------------------------------------

typedef unsigned short ushort;
typedef __attribute__((ext_vector_type(8))) short bf16x8;
typedef __attribute__((ext_vector_type(8))) _Float16 f16x8;
typedef __attribute__((ext_vector_type(4))) float f32x4;

union U16x8 { uint4 q; ushort u[8]; bf16x8 b; f16x8 h; __half2 hh[4]; };

static __device__ __forceinline__ ushort f2bf(float x) {
    union { float f; unsigned u; } a; a.f = x;
    unsigned r = a.u + 0x7FFFu + ((a.u >> 16) & 1u);  // RNE
    return (ushort)(r >> 16);
}
static __device__ __forceinline__ float bf2f(ushort h) {
    union { unsigned u; float f; } a; a.u = ((unsigned)h) << 16;
    return a.f;
}

#define NBUCK 391   // ceil(100000/256)
#define BH_CHUNK 4096
#define BP_CHUNK 2048

// ---------------- bucket histogram -----------------------------------------
__global__ __launch_bounds__(256) void k_bhist(const int* __restrict__ dst,
                                               int* __restrict__ bucketCnt, int E) {
    __shared__ int hist[NBUCK];
    const int t = threadIdx.x;
    const int base = blockIdx.x * BH_CHUNK;
    const int cnt = min(BH_CHUNK, E - base);
    for (int i = t; i < NBUCK; i += 256) hist[i] = 0;
    __syncthreads();
    for (int i = t; i < cnt; i += 256) atomicAdd(&hist[dst[base + i] >> 8], 1);
    __syncthreads();
    for (int i = t; i < NBUCK; i += 256)
        if (hist[i]) atomicAdd(&bucketCnt[i], hist[i]);
}

// ---------------- bucket scan (1 block, 512 thr) ---------------------------
__global__ __launch_bounds__(512) void k_bscan(const int* __restrict__ bucketCnt,
                                               int* __restrict__ bucketBase,
                                               int* __restrict__ bucketCursor) {
    __shared__ int sc[512];
    const int t = threadIdx.x;
    sc[t] = (t < NBUCK) ? bucketCnt[t] : 0;
    __syncthreads();
    for (int off = 1; off < 512; off <<= 1) {
        int a = (t >= off) ? sc[t - off] : 0;
        __syncthreads();
        sc[t] += a;
        __syncthreads();
    }
    if (t <= NBUCK) {
        int base = (t == 0) ? 0 : sc[t - 1];
        bucketBase[t] = base;
        if (t < NBUCK) bucketCursor[t] = base;
    }
}

// ---------------- partition: LDS counting sort per 2048-edge chunk ---------
__global__ __launch_bounds__(256) void k_bpart(const int* __restrict__ src,
                                               const int* __restrict__ dst,
                                               int* __restrict__ bucketCursor,
                                               unsigned* __restrict__ cwTmp, int E) {
    __shared__ unsigned words[BP_CHUNK];
    __shared__ ushort buck[BP_CHUNK];
    __shared__ unsigned sortedW[BP_CHUNK];
    __shared__ ushort buck2[BP_CHUNK];
    __shared__ int sc[512];
    __shared__ int rk[NBUCK];
    __shared__ int runBase[NBUCK];
    const int t = threadIdx.x;
    const int base = blockIdx.x * BP_CHUNK;
    const int cnt = min(BP_CHUNK, E - base);

    sc[t] = 0; sc[t + 256] = 0;
    for (int i = t; i < NBUCK; i += 256) rk[i] = 0;
    __syncthreads();
    for (int i = t; i < cnt; i += 256) {
        int s = src[base + i], d = dst[base + i];
        words[i] = ((unsigned)s << 8) | (unsigned)(d & 255);
        int b = d >> 8;
        buck[i] = (ushort)b;
        atomicAdd(&sc[b], 1);
    }
    __syncthreads();
    for (int off = 1; off < 512; off <<= 1) {
        int a0 = (t >= off) ? sc[t - off] : 0;
        int a1 = (t + 256 >= off) ? sc[t + 256 - off] : 0;
        __syncthreads();
        sc[t] += a0;
        sc[t + 256] += a1;
        __syncthreads();
    }
    for (int i = t; i < cnt; i += 256) {
        int b = buck[i];
        int excl = b ? sc[b - 1] : 0;
        int p = excl + atomicAdd(&rk[b], 1);
        sortedW[p] = words[i];
        buck2[p] = (ushort)b;
    }
    __syncthreads();
    for (int b = t; b < NBUCK; b += 256) {
        int len = rk[b];
        if (len > 0) runBase[b] = atomicAdd(&bucketCursor[b], len);
    }
    __syncthreads();
    for (int i = t; i < cnt; i += 256) {
        int b = buck2[i];
        int excl = b ? sc[b - 1] : 0;
        cwTmp[runBase[b] + (i - excl)] = sortedW[i];
    }
}

// ---------------- finalize: per-bucket node sort -> rowptr, dinv, cw -------
__global__ __launch_bounds__(256) void k_bfin(const unsigned* __restrict__ cwTmp,
                                              const int* __restrict__ bucketBase,
                                              int* __restrict__ cw,
                                              int* __restrict__ rowptr,
                                              float* __restrict__ dinv,
                                              int N, int E) {
    __shared__ int hist[256], sc2[256], rk[256];
    const int b = blockIdx.x, t = threadIdx.x;
    const int gbase = bucketBase[b], gend = bucketBase[b + 1];
    const int n0 = b << 8;
    const int nNodes = min(256, N - n0);
    hist[t] = 0;
    rk[t] = 0;
    __syncthreads();
    for (int i = gbase + t; i < gend; i += 256)
        atomicAdd(&hist[cwTmp[i] & 255u], 1);
    __syncthreads();
    sc2[t] = hist[t];
    __syncthreads();
    for (int off = 1; off < 256; off <<= 1) {
        int a = (t >= off) ? sc2[t - off] : 0;
        __syncthreads();
        sc2[t] += a;
        __syncthreads();
    }
    int ex = sc2[t] - hist[t];  // exclusive
    if (t < nNodes) {
        rowptr[n0 + t] = gbase + ex;
        dinv[n0 + t] = rsqrtf((float)hist[t] + 1.0f);  // +1 self-loop
    }
    if (b == 0 && t == 0) rowptr[N] = E;
    __syncthreads();
    for (int i = gbase + t; i < gend; i += 256) {
        unsigned w = cwTmp[i];
        int dL = w & 255u;
        int r = atomicAdd(&rk[dL], 1);
        cw[gbase + (sc2[dL] - hist[dL]) + r] = (int)(w >> 8);
    }
}

// ---------------- merged weight pre-pack (25 blocks) -----------------------
__global__ __launch_bounds__(256) void k_prep_all(
    const float* __restrict__ W1, const float* __restrict__ Wmu,
    const float* __restrict__ Wls, const float* __restrict__ b1,
    ushort* __restrict__ B1h, ushort* __restrict__ B1l,
    ushort* __restrict__ B2h, ushort* __restrict__ B2l,
    float* __restrict__ b1p) {
    const int b = blockIdx.x, t = threadIdx.x;
    if (b < 16) {
        int i = b * 256 + t;  // 32*128 entries
        int kgrp = i >> 7, col = i & 127;
        U16x8 h, l;
#pragma unroll
        for (int j = 0; j < 8; ++j) {
            float x = W1[(size_t)(kgrp * 8 + j) * 128 + col];
            h.u[j] = f2bf(x);
            l.u[j] = f2bf(x - bf2f(h.u[j]));
        }
        *(uint4*)(B1h + (size_t)i * 8) = h.q;
        *(uint4*)(B1l + (size_t)i * 8) = l.q;
    } else if (b < 24) {
        int i = (b - 16) * 256 + t;  // 16*128 entries
        int kgrp = i >> 7, col = i & 127;
        U16x8 h, l;
#pragma unroll
        for (int j = 0; j < 8; ++j) {
            int lk = j * 16 + kgrp;  // stored_k -> logical hidden index
            float x = (col < 64) ? Wmu[(size_t)lk * 64 + col]
                                 : Wls[(size_t)lk * 64 + col - 64];
            __half hh = __float2half(x);
            __half ll = __float2half(x - __half2float(hh));
            h.u[j] = __half_as_ushort(hh);
            l.u[j] = __half_as_ushort(ll);
        }
        *(uint4*)(B2h + (size_t)i * 8) = h.q;
        *(uint4*)(B2l + (size_t)i * 8) = l.q;
    } else {
        if (t < 128) b1p[t] = b1[(t & 7) * 16 + (t >> 3)];
    }
}

// ---------------- GEMM1: h1' = dinv * (x @ W1), group-major fp16 -----------
// Output layout: H[(s>>4)*M*16 + row*16 + (s&15)] for stored channel s.
__global__ __launch_bounds__(256) void k_gemm1(const float* __restrict__ A,
                                               const ushort* __restrict__ Bph,
                                               const ushort* __restrict__ Bpl,
                                               const float* __restrict__ dinv,
                                               __half* __restrict__ H1, int M) {
    const int t = threadIdx.x, lane = t & 63;
    const int kgrp = lane >> 4, lrow = lane & 15;
    const int rowBase = blockIdx.x * 128 + (t >> 6) * 32;

    f32x4 acc[2][8];
#pragma unroll
    for (int mf = 0; mf < 2; ++mf)
#pragma unroll
        for (int nf = 0; nf < 8; ++nf) acc[mf][nf] = (f32x4)0.f;

    for (int c = 0; c < 8; ++c) {  // K=256
        bf16x8 ah[2], al[2];
#pragma unroll
        for (int mf = 0; mf < 2; ++mf) {
            int r = rowBase + mf * 16 + lrow;
            if (r >= M) r = M - 1;
            const float* ap = A + (size_t)r * 256 + c * 32 + kgrp * 8;
            float4 x0 = *(const float4*)ap;
            float4 x1 = *(const float4*)(ap + 4);
            float v[8] = {x0.x, x0.y, x0.z, x0.w, x1.x, x1.y, x1.z, x1.w};
            U16x8 h, l;
#pragma unroll
            for (int i = 0; i < 8; ++i) {
                h.u[i] = f2bf(v[i]);
                l.u[i] = f2bf(v[i] - bf2f(h.u[i]));
            }
            ah[mf] = h.b;
            al[mf] = l.b;
        }
#pragma unroll
        for (int nf = 0; nf < 8; ++nf) {
            size_t bo = ((size_t)(c * 4 + kgrp) * 128 + nf * 16 + lrow) * 8;
            U16x8 bh, bl;
            bh.q = *(const uint4*)(Bph + bo);
            bl.q = *(const uint4*)(Bpl + bo);
#pragma unroll
            for (int mf = 0; mf < 2; ++mf) {
                acc[mf][nf] = __builtin_amdgcn_mfma_f32_16x16x32_bf16(
                    ah[mf], bh.b, acc[mf][nf], 0, 0, 0);
                acc[mf][nf] = __builtin_amdgcn_mfma_f32_16x16x32_bf16(
                    ah[mf], bl.b, acc[mf][nf], 0, 0, 0);
                acc[mf][nf] = __builtin_amdgcn_mfma_f32_16x16x32_bf16(
                    al[mf], bh.b, acc[mf][nf], 0, 0, 0);
            }
        }
    }
    // epilogue: stored s = lrow*8+nf -> group lrow>>1, offset (lrow&1)*8+nf
#pragma unroll
    for (int mf = 0; mf < 2; ++mf)
#pragma unroll
        for (int reg = 0; reg < 4; ++reg) {
            int row = rowBase + mf * 16 + kgrp * 4 + reg;
            if (row < M) {
                float dv = dinv[row];
                union { uint4 q; __half h[8]; } o;
#pragma unroll
                for (int nf = 0; nf < 8; ++nf)
                    o.h[nf] = __float2half(acc[mf][nf][reg] * dv);
                *(uint4*)(H1 + ((size_t)(lrow >> 1) * M + row) * 16 +
                          (lrow & 1) * 8) = o.q;
            }
        }
}

// ---------------- channel-sharded CSR gather -------------------------------
// group = blockIdx&7 (round-robin XCD => group pinned to one XCD; its 3.2MB
// H_g array is L2-resident). Wave = 1 node x 16 ch; 8 lanes/edge, 8 edges
// per load, 32 edges in flight. cw/rowptr nontemporal (don't thrash H_g).
// EPI==1: out = dinv*relu(dinv*acc + b1p);  EPI==0: out = dinv*acc.
template <int EPI>
__global__ __launch_bounds__(256) void k_agg_g(const __half* __restrict__ Hin,
                                               const int* __restrict__ rowptr,
                                               const int* __restrict__ cw,
                                               const float* __restrict__ dinv,
                                               const float* __restrict__ b1p,
                                               __half* __restrict__ Hout, int N) {
    const int g = blockIdx.x & 7;
    const int node = (blockIdx.x >> 3) * 4 + (threadIdx.x >> 6);
    if (node >= N) return;
    const int lane = threadIdx.x & 63;
    const int sub = lane >> 3, lr = lane & 7;
    const __half* Hg = Hin + (size_t)g * N * 16;

    float2 acc = make_float2(0.f, 0.f);
    if (sub == 0)
        acc = __half22float2(((const __half2*)(Hg + (size_t)node * 16))[lr]);

    const int start = rowptr[node], end = rowptr[node + 1];
    for (int e = start; e < end; e += 32) {
#pragma unroll
        for (int q = 0; q < 4; ++q) {
            int ee = e + q * 8 + sub;
            if (ee < end) {
                int s = __builtin_nontemporal_load(cw + ee);
                float2 f =
                    __half22float2(((const __half2*)(Hg + (size_t)s * 16))[lr]);
                acc.x += f.x;
                acc.y += f.y;
            }
        }
    }
#pragma unroll
    for (int m = 8; m < 64; m <<= 1) {
        acc.x += __shfl_xor(acc.x, m);
        acc.y += __shfl_xor(acc.y, m);
    }
    if (sub == 0) {
        float dv = dinv[node];
        if (EPI == 1) {
            float2 bb = ((const float2*)b1p)[g * 8 + lr];
            acc.x = fmaxf(fmaf(acc.x, dv, bb.x), 0.f) * dv;
            acc.y = fmaxf(fmaf(acc.y, dv, bb.y), 0.f) * dv;
        } else {
            acc.x *= dv;
            acc.y *= dv;
        }
        ((__half2*)(Hout + ((size_t)g * N + node) * 16))[lr] =
            __float22half2_rn(acc);
    }
}

// ---------------- GEMM2: [mu|ls] = agg2 @ [Wmu|Wls] + bias -----------------
// A group-major fp16: stored chunk c*32+kgrp*8 -> group c*2+(kgrp>>1).
__global__ __launch_bounds__(256) void k_gemm2(const __half* __restrict__ A,
                                               const ushort* __restrict__ Bph,
                                               const ushort* __restrict__ Bpl,
                                               float* __restrict__ Cmu,
                                               float* __restrict__ Cls,
                                               const float* __restrict__ bmu,
                                               const float* __restrict__ bls, int M) {
    const int t = threadIdx.x, lane = t & 63;
    const int kgrp = lane >> 4, lrow = lane & 15;
    const int rowBase = blockIdx.x * 128 + (t >> 6) * 32;

    f32x4 acc[2][8];
#pragma unroll
    for (int mf = 0; mf < 2; ++mf)
#pragma unroll
        for (int nf = 0; nf < 8; ++nf) acc[mf][nf] = (f32x4)0.f;

    for (int c = 0; c < 4; ++c) {  // K=128 stored
        f16x8 a[2];
        const int gg = c * 2 + (kgrp >> 1);
#pragma unroll
        for (int mf = 0; mf < 2; ++mf) {
            int r = rowBase + mf * 16 + lrow;
            if (r >= M) r = M - 1;
            U16x8 u;
            u.q = *(const uint4*)(A + ((size_t)gg * M + r) * 16 + (kgrp & 1) * 8);
            a[mf] = u.h;
        }
#pragma unroll
        for (int nf = 0; nf < 8; ++nf) {
            size_t bo = ((size_t)(c * 4 + kgrp) * 128 + nf * 16 + lrow) * 8;
            U16x8 bh, bl;
            bh.q = *(const uint4*)(Bph + bo);
            bl.q = *(const uint4*)(Bpl + bo);
#pragma unroll
            for (int mf = 0; mf < 2; ++mf) {
                acc[mf][nf] = __builtin_amdgcn_mfma_f32_16x16x32_f16(
                    a[mf], bh.h, acc[mf][nf], 0, 0, 0);
                acc[mf][nf] = __builtin_amdgcn_mfma_f32_16x16x32_f16(
                    a[mf], bl.h, acc[mf][nf], 0, 0, 0);
            }
        }
    }
    float bv[8];
#pragma unroll
    for (int nf = 0; nf < 8; ++nf)
        bv[nf] = (nf < 4) ? bmu[nf * 16 + lrow] : bls[(nf - 4) * 16 + lrow];
#pragma unroll
    for (int mf = 0; mf < 2; ++mf)
#pragma unroll
        for (int reg = 0; reg < 4; ++reg) {
            int row = rowBase + mf * 16 + kgrp * 4 + reg;
            if (row < M) {
#pragma unroll
                for (int nf = 0; nf < 4; ++nf)
                    __builtin_nontemporal_store(
                        acc[mf][nf][reg] + bv[nf],
                        &Cmu[(size_t)row * 64 + nf * 16 + lrow]);
#pragma unroll
                for (int nf = 4; nf < 8; ++nf)
                    __builtin_nontemporal_store(
                        acc[mf][nf][reg] + bv[nf],
                        &Cls[(size_t)row * 64 + (nf - 4) * 16 + lrow]);
            }
        }
}

extern "C" void kernel_launch(void* const* d_in, const int* in_sizes, int n_in,
                              void* d_out, int out_size, void* d_ws, size_t ws_size,
                              hipStream_t stream) {
    const float* x   = (const float*)d_in[0];
    const int*   ei  = (const int*)d_in[1];
    const float* W1  = (const float*)d_in[2];
    const float* b1  = (const float*)d_in[3];
    const float* Wmu = (const float*)d_in[4];
    const float* bmu = (const float*)d_in[5];
    const float* Wls = (const float*)d_in[6];
    const float* bls = (const float*)d_in[7];

    const int N = in_sizes[0] / 256;  // 100000
    const int E = in_sizes[1] / 2;    // 1600000
    const int* src = ei;
    const int* dst = ei + E;

    float* out_mu = (float*)d_out;
    float* out_ls = out_mu + (size_t)N * 64;

    // ---- workspace layout ----
    char* wsb = (char*)d_ws;
    const size_t KB = 1024, MB = 1024 * 1024;
    const size_t Hh_BYTES = (size_t)N * 128 * 2;  // 25.6 MB
    int*      bucketCnt    = (int*)(wsb + 0);
    int*      bucketBase   = (int*)(wsb + 4 * KB);
    int*      bucketCursor = (int*)(wsb + 8 * KB);
    float*    b1p          = (float*)(wsb + 16 * KB);
    ushort*   Bp1h         = (ushort*)(wsb + 32 * KB);
    ushort*   Bp1l         = (ushort*)(wsb + 96 * KB);
    ushort*   Bp2h         = (ushort*)(wsb + 160 * KB);
    ushort*   Bp2l         = (ushort*)(wsb + 192 * KB);
    int*      rowptr       = (int*)(wsb + 256 * KB);
    float*    dinv         = (float*)(wsb + 768 * KB);
    unsigned* cwTmp        = (unsigned*)(wsb + 1280 * KB);  // 6.4 MB
    int*      cw           = (int*)(wsb + 8 * MB);          // 6.4 MB
    __half*   h1           = (__half*)(wsb + 15 * MB);      // 25.6 MB
    __half*   hbuf;                                         // h'
    __half*   agg2;
    if (ws_size >= 67 * MB + Hh_BYTES) {
        hbuf = (__half*)(wsb + 41 * MB);
        agg2 = (__half*)(wsb + 67 * MB);
    } else {
        hbuf = (__half*)d_out;  // 25.6 <= 51.2 MB; d_out rewritten by GEMM2
        agg2 = (__half*)(wsb + 41 * MB);
    }

    const int nChunksH = (E + BH_CHUNK - 1) / BH_CHUNK;  // 391
    const int nChunksP = (E + BP_CHUNK - 1) / BP_CHUNK;  // 782
    const int nBlkAggG = ((N + 3) / 4) * 8;              // 8 channel groups
    const int nBlkGemm = (N + 127) / 128;

    // ---- CSR build (bucketed counting sort) ----
    hipMemsetAsync(bucketCnt, 0, 392 * 4, stream);
    k_bhist<<<nChunksH, 256, 0, stream>>>(dst, bucketCnt, E);
    k_bscan<<<1, 512, 0, stream>>>(bucketCnt, bucketBase, bucketCursor);
    k_bpart<<<nChunksP, 256, 0, stream>>>(src, dst, bucketCursor, cwTmp, E);
    k_bfin<<<NBUCK, 256, 0, stream>>>(cwTmp, bucketBase, cw, rowptr, dinv, N, E);

    // ---- weight prepacks (single launch) ----
    k_prep_all<<<25, 256, 0, stream>>>(W1, Wmu, Wls, b1, Bp1h, Bp1l, Bp2h, Bp2l, b1p);

    // ---- layer 1 ----
    k_gemm1<<<nBlkGemm, 256, 0, stream>>>(x, Bp1h, Bp1l, dinv, h1, N);
    k_agg_g<1><<<nBlkAggG, 256, 0, stream>>>(h1, rowptr, cw, dinv, b1p, hbuf, N);

    // ---- layer 2 ----
    k_agg_g<0><<<nBlkAggG, 256, 0, stream>>>(hbuf, rowptr, cw, dinv, nullptr, agg2, N);
    k_gemm2<<<nBlkGemm, 256, 0, stream>>>(agg2, Bp2h, Bp2l, out_mu, out_ls,
                                          bmu, bls, N);
}

// Round 9
// 277.402 us; speedup vs baseline: 2.5906x; 2.5906x over previous
//
#include <hip/hip_runtime.h>
#include <hip/hip_fp16.h>

// ---------------------------------------------------------------------------
// VariationalGCNEncoder: mu/logstd = GCNConv(relu(GCNConv(x)))
// N=100000, E=1600000, IN=256, HID=128, OUT=64
//
// R9: R7 structure (R8's channel-sharding regressed 4.5x: small scattered
//     L2 requests lose to big random rows).
//     (a) gemm1 uses f16 split: A = f16(x) (no lo term needed), B = f16
//         hi/lo => 2 MFMAs instead of 3, cheap cvt.
//     (b) k_bscan deleted: bpart/bfin do redundant local 391-scan of
//         bucketCnt + zero-based cursors.
// Pipeline: memset -> bhist -> bpart -> bfin | prep_all | gemm1 -> agg<1>
//           -> agg<0> -> gemm2
// ---------------------------------------------------------------------------

typedef unsigned short ushort;
typedef __attribute__((ext_vector_type(8))) short bf16x8;
typedef __attribute__((ext_vector_type(8))) _Float16 f16x8;
typedef __attribute__((ext_vector_type(4))) float f32x4;

union U16x8 { uint4 q; ushort u[8]; bf16x8 b; f16x8 h; __half2 hh[4]; };

#define NBUCK 391   // ceil(100000/256)
#define BH_CHUNK 4096
#define BP_CHUNK 2048

// ---------------- bucket histogram -----------------------------------------
__global__ __launch_bounds__(256) void k_bhist(const int* __restrict__ dst,
                                               int* __restrict__ bucketCnt, int E) {
    __shared__ int hist[NBUCK];
    const int t = threadIdx.x;
    const int base = blockIdx.x * BH_CHUNK;
    const int cnt = min(BH_CHUNK, E - base);
    for (int i = t; i < NBUCK; i += 256) hist[i] = 0;
    __syncthreads();
    for (int i = t; i < cnt; i += 256) atomicAdd(&hist[dst[base + i] >> 8], 1);
    __syncthreads();
    for (int i = t; i < NBUCK; i += 256)
        if (hist[i]) atomicAdd(&bucketCnt[i], hist[i]);
}

// ---------------- partition: LDS counting sort per 2048-edge chunk ---------
// Bucket bases computed locally (inclusive scan of bucketCnt in LDS);
// run reservation via zero-based cur0.
__global__ __launch_bounds__(256) void k_bpart(const int* __restrict__ src,
                                               const int* __restrict__ dst,
                                               const int* __restrict__ bucketCnt,
                                               int* __restrict__ cur0,
                                               unsigned* __restrict__ cwTmp, int E) {
    __shared__ unsigned words[BP_CHUNK];
    __shared__ ushort buck[BP_CHUNK];
    __shared__ unsigned sortedW[BP_CHUNK];
    __shared__ ushort buck2[BP_CHUNK];
    __shared__ int sc[512];
    __shared__ int gsc[512];
    __shared__ int rk[NBUCK];
    __shared__ int runBase[NBUCK];
    const int t = threadIdx.x;
    const int base = blockIdx.x * BP_CHUNK;
    const int cnt = min(BP_CHUNK, E - base);

    // phase 0: local inclusive scan of global bucket counts
    gsc[t] = (t < NBUCK) ? bucketCnt[t] : 0;
    gsc[t + 256] = (t + 256 < NBUCK) ? bucketCnt[t + 256] : 0;
    sc[t] = 0; sc[t + 256] = 0;
    for (int i = t; i < NBUCK; i += 256) rk[i] = 0;
    __syncthreads();
    for (int off = 1; off < 512; off <<= 1) {
        int a0 = (t >= off) ? gsc[t - off] : 0;
        int a1 = (t + 256 >= off) ? gsc[t + 256 - off] : 0;
        __syncthreads();
        gsc[t] += a0;
        gsc[t + 256] += a1;
        __syncthreads();
    }
    // phase 1: load + per-chunk histogram
    for (int i = t; i < cnt; i += 256) {
        int s = src[base + i], d = dst[base + i];
        words[i] = ((unsigned)s << 8) | (unsigned)(d & 255);
        int b = d >> 8;
        buck[i] = (ushort)b;
        atomicAdd(&sc[b], 1);
    }
    __syncthreads();
    for (int off = 1; off < 512; off <<= 1) {
        int a0 = (t >= off) ? sc[t - off] : 0;
        int a1 = (t + 256 >= off) ? sc[t + 256 - off] : 0;
        __syncthreads();
        sc[t] += a0;
        sc[t + 256] += a1;
        __syncthreads();
    }
    // phase 2: scatter into bucket-sorted LDS order
    for (int i = t; i < cnt; i += 256) {
        int b = buck[i];
        int excl = b ? sc[b - 1] : 0;
        int p = excl + atomicAdd(&rk[b], 1);
        sortedW[p] = words[i];
        buck2[p] = (ushort)b;
    }
    __syncthreads();
    // phase 3: reserve global runs (one atomic per non-empty bucket)
    for (int b = t; b < NBUCK; b += 256) {
        int len = rk[b];
        if (len > 0) {
            int gbase = b ? gsc[b - 1] : 0;
            runBase[b] = gbase + atomicAdd(&cur0[b], len);
        }
    }
    __syncthreads();
    // phase 4: coalesced write-out of sorted runs
    for (int i = t; i < cnt; i += 256) {
        int b = buck2[i];
        int excl = b ? sc[b - 1] : 0;
        cwTmp[runBase[b] + (i - excl)] = sortedW[i];
    }
}

// ---------------- finalize: per-bucket node sort -> rowptr, dinv, cw -------
__global__ __launch_bounds__(256) void k_bfin(const unsigned* __restrict__ cwTmp,
                                              const int* __restrict__ bucketCnt,
                                              int* __restrict__ cw,
                                              int* __restrict__ rowptr,
                                              float* __restrict__ dinv,
                                              int N, int E) {
    __shared__ int hist[256], sc2[256], rk[256];
    __shared__ int gsc[512];
    const int b = blockIdx.x, t = threadIdx.x;
    gsc[t] = (t < NBUCK) ? bucketCnt[t] : 0;
    gsc[t + 256] = (t + 256 < NBUCK) ? bucketCnt[t + 256] : 0;
    hist[t] = 0;
    rk[t] = 0;
    __syncthreads();
    for (int off = 1; off < 512; off <<= 1) {
        int a0 = (t >= off) ? gsc[t - off] : 0;
        int a1 = (t + 256 >= off) ? gsc[t + 256 - off] : 0;
        __syncthreads();
        gsc[t] += a0;
        gsc[t + 256] += a1;
        __syncthreads();
    }
    const int gbase = b ? gsc[b - 1] : 0;
    const int gend = gsc[b];
    const int n0 = b << 8;
    const int nNodes = min(256, N - n0);
    for (int i = gbase + t; i < gend; i += 256)
        atomicAdd(&hist[cwTmp[i] & 255u], 1);
    __syncthreads();
    sc2[t] = hist[t];
    __syncthreads();
    for (int off = 1; off < 256; off <<= 1) {
        int a = (t >= off) ? sc2[t - off] : 0;
        __syncthreads();
        sc2[t] += a;
        __syncthreads();
    }
    int ex = sc2[t] - hist[t];  // exclusive
    if (t < nNodes) {
        rowptr[n0 + t] = gbase + ex;
        dinv[n0 + t] = rsqrtf((float)hist[t] + 1.0f);  // +1 self-loop
    }
    if (b == 0 && t == 0) rowptr[N] = E;
    __syncthreads();
    for (int i = gbase + t; i < gend; i += 256) {
        unsigned w = cwTmp[i];
        int dL = w & 255u;
        int r = atomicAdd(&rk[dL], 1);
        cw[gbase + (sc2[dL] - hist[dL]) + r] = (int)(w >> 8);
    }
}

// ---------------- merged weight pre-pack (25 blocks) -----------------------
// blocks 0..15: B1 f16 hi/lo, layout [kgrp=k/8][col][k%8], logical k.
// blocks 16..23: B2 [Wmu|Wls] f16 hi/lo, K-rows permuted: lk = j*16+kgrp.
// block 24: b1p[j] = b1[(j&7)*16 + (j>>3)]
__global__ __launch_bounds__(256) void k_prep_all(
    const float* __restrict__ W1, const float* __restrict__ Wmu,
    const float* __restrict__ Wls, const float* __restrict__ b1,
    ushort* __restrict__ B1h, ushort* __restrict__ B1l,
    ushort* __restrict__ B2h, ushort* __restrict__ B2l,
    float* __restrict__ b1p) {
    const int b = blockIdx.x, t = threadIdx.x;
    if (b < 16) {
        int i = b * 256 + t;  // 32*128 entries
        int kgrp = i >> 7, col = i & 127;
        U16x8 h, l;
#pragma unroll
        for (int j = 0; j < 8; ++j) {
            float x = W1[(size_t)(kgrp * 8 + j) * 128 + col];
            __half hh = __float2half(x);
            __half ll = __float2half(x - __half2float(hh));
            h.u[j] = __half_as_ushort(hh);
            l.u[j] = __half_as_ushort(ll);
        }
        *(uint4*)(B1h + (size_t)i * 8) = h.q;
        *(uint4*)(B1l + (size_t)i * 8) = l.q;
    } else if (b < 24) {
        int i = (b - 16) * 256 + t;  // 16*128 entries
        int kgrp = i >> 7, col = i & 127;
        U16x8 h, l;
#pragma unroll
        for (int j = 0; j < 8; ++j) {
            int lk = j * 16 + kgrp;  // stored_k -> logical hidden index
            float x = (col < 64) ? Wmu[(size_t)lk * 64 + col]
                                 : Wls[(size_t)lk * 64 + col - 64];
            __half hh = __float2half(x);
            __half ll = __float2half(x - __half2float(hh));
            h.u[j] = __half_as_ushort(hh);
            l.u[j] = __half_as_ushort(ll);
        }
        *(uint4*)(B2h + (size_t)i * 8) = h.q;
        *(uint4*)(B2l + (size_t)i * 8) = l.q;
    } else {
        if (t < 128) b1p[t] = b1[(t & 7) * 16 + (t >> 3)];
    }
}

// ---------------- GEMM1: h1' = dinv * (x @ W1), fp16 stored-order ----------
// A = f16(x) (single term; residual al*b ~1e-4 << fp16 storage error),
// B = f16 hi/lo => 2 MFMAs per frag-pair. No LDS, no barriers.
__global__ __launch_bounds__(256) void k_gemm1(const float* __restrict__ A,
                                               const ushort* __restrict__ Bph,
                                               const ushort* __restrict__ Bpl,
                                               const float* __restrict__ dinv,
                                               __half* __restrict__ H1, int M) {
    const int t = threadIdx.x, lane = t & 63;
    const int kgrp = lane >> 4, lrow = lane & 15;
    const int rowBase = blockIdx.x * 128 + (t >> 6) * 32;

    f32x4 acc[2][8];
#pragma unroll
    for (int mf = 0; mf < 2; ++mf)
#pragma unroll
        for (int nf = 0; nf < 8; ++nf) acc[mf][nf] = (f32x4)0.f;

    for (int c = 0; c < 8; ++c) {  // K=256
        f16x8 ah[2];
#pragma unroll
        for (int mf = 0; mf < 2; ++mf) {
            int r = rowBase + mf * 16 + lrow;
            if (r >= M) r = M - 1;
            const float* ap = A + (size_t)r * 256 + c * 32 + kgrp * 8;
            float4 x0 = *(const float4*)ap;
            float4 x1 = *(const float4*)(ap + 4);
            float v[8] = {x0.x, x0.y, x0.z, x0.w, x1.x, x1.y, x1.z, x1.w};
            U16x8 h;
#pragma unroll
            for (int i = 0; i < 8; ++i)
                h.u[i] = __half_as_ushort(__float2half(v[i]));
            ah[mf] = h.h;
        }
#pragma unroll
        for (int nf = 0; nf < 8; ++nf) {
            size_t bo = ((size_t)(c * 4 + kgrp) * 128 + nf * 16 + lrow) * 8;
            U16x8 bh, bl;
            bh.q = *(const uint4*)(Bph + bo);
            bl.q = *(const uint4*)(Bpl + bo);
#pragma unroll
            for (int mf = 0; mf < 2; ++mf) {
                acc[mf][nf] = __builtin_amdgcn_mfma_f32_16x16x32_f16(
                    ah[mf], bh.h, acc[mf][nf], 0, 0, 0);
                acc[mf][nf] = __builtin_amdgcn_mfma_f32_16x16x32_f16(
                    ah[mf], bl.h, acc[mf][nf], 0, 0, 0);
            }
        }
    }
#pragma unroll
    for (int mf = 0; mf < 2; ++mf)
#pragma unroll
        for (int reg = 0; reg < 4; ++reg) {
            int row = rowBase + mf * 16 + kgrp * 4 + reg;
            if (row < M) {
                float dv = dinv[row];
                union { uint4 q; __half h[8]; } o;
#pragma unroll
                for (int nf = 0; nf < 8; ++nf)
                    o.h[nf] = __float2half(acc[mf][nf][reg] * dv);
                *(uint4*)(H1 + (size_t)row * 128 + lrow * 8) = o.q;
            }
        }
}

// ---------------- CSR gather (pure adds; rows pre-scaled) ------------------
// EPI==1: out = dinv * relu(dinv*acc + b1p)   (stored order)
// EPI==0: out = dinv * acc                    (true agg2, GEMM2 input)
template <int EPI>
__global__ __launch_bounds__(256) void k_agg(const __half* __restrict__ Hin,
                                             const int* __restrict__ rowptr,
                                             const int* __restrict__ cw,
                                             const float* __restrict__ dinv,
                                             const float* __restrict__ b1p,
                                             __half* __restrict__ Hout, int N) {
    int node = (blockIdx.x * 256 + threadIdx.x) >> 6;
    int lane = threadIdx.x & 63;
    if (node >= N) return;
    float2 acc = __half22float2(((const __half2*)(Hin + (size_t)node * 128))[lane]);
    int e = rowptr[node], end = rowptr[node + 1];
    for (; e + 8 <= end; e += 8) {
        int s0 = cw[e], s1 = cw[e + 1], s2 = cw[e + 2], s3 = cw[e + 3];
        int s4 = cw[e + 4], s5 = cw[e + 5], s6 = cw[e + 6], s7 = cw[e + 7];
        float2 f0 = __half22float2(((const __half2*)(Hin + (size_t)s0 * 128))[lane]);
        float2 f1 = __half22float2(((const __half2*)(Hin + (size_t)s1 * 128))[lane]);
        float2 f2 = __half22float2(((const __half2*)(Hin + (size_t)s2 * 128))[lane]);
        float2 f3 = __half22float2(((const __half2*)(Hin + (size_t)s3 * 128))[lane]);
        float2 f4 = __half22float2(((const __half2*)(Hin + (size_t)s4 * 128))[lane]);
        float2 f5 = __half22float2(((const __half2*)(Hin + (size_t)s5 * 128))[lane]);
        float2 f6 = __half22float2(((const __half2*)(Hin + (size_t)s6 * 128))[lane]);
        float2 f7 = __half22float2(((const __half2*)(Hin + (size_t)s7 * 128))[lane]);
        acc.x += f0.x; acc.y += f0.y; acc.x += f1.x; acc.y += f1.y;
        acc.x += f2.x; acc.y += f2.y; acc.x += f3.x; acc.y += f3.y;
        acc.x += f4.x; acc.y += f4.y; acc.x += f5.x; acc.y += f5.y;
        acc.x += f6.x; acc.y += f6.y; acc.x += f7.x; acc.y += f7.y;
    }
    for (; e + 2 <= end; e += 2) {
        int s0 = cw[e], s1 = cw[e + 1];
        float2 f0 = __half22float2(((const __half2*)(Hin + (size_t)s0 * 128))[lane]);
        float2 f1 = __half22float2(((const __half2*)(Hin + (size_t)s1 * 128))[lane]);
        acc.x += f0.x; acc.y += f0.y; acc.x += f1.x; acc.y += f1.y;
    }
    if (e < end) {
        int s0 = cw[e];
        float2 f0 = __half22float2(((const __half2*)(Hin + (size_t)s0 * 128))[lane]);
        acc.x += f0.x; acc.y += f0.y;
    }
    float dv = dinv[node];
    if (EPI == 1) {
        float2 bb = ((const float2*)b1p)[lane];
        acc.x = fmaxf(fmaf(acc.x, dv, bb.x), 0.f) * dv;
        acc.y = fmaxf(fmaf(acc.y, dv, bb.y), 0.f) * dv;
    } else {
        acc.x *= dv;
        acc.y *= dv;
    }
    ((__half2*)(Hout + (size_t)node * 128))[lane] = __float22half2_rn(acc);
}

// ---------------- GEMM2: [mu|ls] = agg2 @ [Wmu|Wls] + bias -----------------
__global__ __launch_bounds__(256) void k_gemm2(const __half* __restrict__ A,
                                               const ushort* __restrict__ Bph,
                                               const ushort* __restrict__ Bpl,
                                               float* __restrict__ Cmu,
                                               float* __restrict__ Cls,
                                               const float* __restrict__ bmu,
                                               const float* __restrict__ bls, int M) {
    const int t = threadIdx.x, lane = t & 63;
    const int kgrp = lane >> 4, lrow = lane & 15;
    const int rowBase = blockIdx.x * 128 + (t >> 6) * 32;

    f32x4 acc[2][8];
#pragma unroll
    for (int mf = 0; mf < 2; ++mf)
#pragma unroll
        for (int nf = 0; nf < 8; ++nf) acc[mf][nf] = (f32x4)0.f;

    for (int c = 0; c < 4; ++c) {  // K=128 stored
        f16x8 a[2];
#pragma unroll
        for (int mf = 0; mf < 2; ++mf) {
            int r = rowBase + mf * 16 + lrow;
            if (r >= M) r = M - 1;
            U16x8 u;
            u.q = *(const uint4*)(A + (size_t)r * 128 + c * 32 + kgrp * 8);
            a[mf] = u.h;
        }
#pragma unroll
        for (int nf = 0; nf < 8; ++nf) {
            size_t bo = ((size_t)(c * 4 + kgrp) * 128 + nf * 16 + lrow) * 8;
            U16x8 bh, bl;
            bh.q = *(const uint4*)(Bph + bo);
            bl.q = *(const uint4*)(Bpl + bo);
#pragma unroll
            for (int mf = 0; mf < 2; ++mf) {
                acc[mf][nf] = __builtin_amdgcn_mfma_f32_16x16x32_f16(
                    a[mf], bh.h, acc[mf][nf], 0, 0, 0);
                acc[mf][nf] = __builtin_amdgcn_mfma_f32_16x16x32_f16(
                    a[mf], bl.h, acc[mf][nf], 0, 0, 0);
            }
        }
    }
    float bv[8];
#pragma unroll
    for (int nf = 0; nf < 8; ++nf)
        bv[nf] = (nf < 4) ? bmu[nf * 16 + lrow] : bls[(nf - 4) * 16 + lrow];
#pragma unroll
    for (int mf = 0; mf < 2; ++mf)
#pragma unroll
        for (int reg = 0; reg < 4; ++reg) {
            int row = rowBase + mf * 16 + kgrp * 4 + reg;
            if (row < M) {
#pragma unroll
                for (int nf = 0; nf < 4; ++nf)
                    __builtin_nontemporal_store(
                        acc[mf][nf][reg] + bv[nf],
                        &Cmu[(size_t)row * 64 + nf * 16 + lrow]);
#pragma unroll
                for (int nf = 4; nf < 8; ++nf)
                    __builtin_nontemporal_store(
                        acc[mf][nf][reg] + bv[nf],
                        &Cls[(size_t)row * 64 + (nf - 4) * 16 + lrow]);
            }
        }
}

extern "C" void kernel_launch(void* const* d_in, const int* in_sizes, int n_in,
                              void* d_out, int out_size, void* d_ws, size_t ws_size,
                              hipStream_t stream) {
    const float* x   = (const float*)d_in[0];
    const int*   ei  = (const int*)d_in[1];
    const float* W1  = (const float*)d_in[2];
    const float* b1  = (const float*)d_in[3];
    const float* Wmu = (const float*)d_in[4];
    const float* bmu = (const float*)d_in[5];
    const float* Wls = (const float*)d_in[6];
    const float* bls = (const float*)d_in[7];

    const int N = in_sizes[0] / 256;  // 100000
    const int E = in_sizes[1] / 2;    // 1600000
    const int* src = ei;
    const int* dst = ei + E;

    float* out_mu = (float*)d_out;
    float* out_ls = out_mu + (size_t)N * 64;

    // ---- workspace layout ----
    char* wsb = (char*)d_ws;
    const size_t KB = 1024, MB = 1024 * 1024;
    const size_t Hh_BYTES = (size_t)N * 128 * 2;  // 25.6 MB
    int*      bucketCnt = (int*)(wsb + 0);           // 392 ints
    int*      cur0      = (int*)(wsb + 2 * KB);      // 392 ints (zeroed)
    float*    b1p       = (float*)(wsb + 16 * KB);
    ushort*   Bp1h      = (ushort*)(wsb + 32 * KB);  // 64 KB
    ushort*   Bp1l      = (ushort*)(wsb + 96 * KB);  // 64 KB
    ushort*   Bp2h      = (ushort*)(wsb + 160 * KB); // 32 KB
    ushort*   Bp2l      = (ushort*)(wsb + 192 * KB); // 32 KB
    int*      rowptr    = (int*)(wsb + 256 * KB);
    float*    dinv      = (float*)(wsb + 768 * KB);
    unsigned* cwTmp     = (unsigned*)(wsb + 1280 * KB);  // 6.4 MB
    int*      cw        = (int*)(wsb + 8 * MB);          // 6.4 MB
    __half*   h1        = (__half*)(wsb + 15 * MB);      // 25.6 MB
    __half*   hbuf;                                      // h'
    __half*   agg2;
    if (ws_size >= 67 * MB + Hh_BYTES) {
        hbuf = (__half*)(wsb + 41 * MB);
        agg2 = (__half*)(wsb + 67 * MB);
    } else {
        hbuf = (__half*)d_out;  // 25.6 <= 51.2 MB; d_out rewritten by GEMM2
        agg2 = (__half*)(wsb + 41 * MB);
    }

    const int nChunksH = (E + BH_CHUNK - 1) / BH_CHUNK;  // 391
    const int nChunksP = (E + BP_CHUNK - 1) / BP_CHUNK;  // 782
    const int nBlkAgg  = (N + 3) / 4;
    const int nBlkGemm = (N + 127) / 128;

    // ---- CSR build (bucketed counting sort, no separate scan kernel) ----
    hipMemsetAsync(wsb, 0, 4 * KB, stream);  // bucketCnt + cur0
    k_bhist<<<nChunksH, 256, 0, stream>>>(dst, bucketCnt, E);
    k_bpart<<<nChunksP, 256, 0, stream>>>(src, dst, bucketCnt, cur0, cwTmp, E);
    k_bfin<<<NBUCK, 256, 0, stream>>>(cwTmp, bucketCnt, cw, rowptr, dinv, N, E);

    // ---- weight prepacks (single launch) ----
    k_prep_all<<<25, 256, 0, stream>>>(W1, Wmu, Wls, b1, Bp1h, Bp1l, Bp2h, Bp2l, b1p);

    // ---- layer 1 ----
    k_gemm1<<<nBlkGemm, 256, 0, stream>>>(x, Bp1h, Bp1l, dinv, h1, N);
    k_agg<1><<<nBlkAgg, 256, 0, stream>>>(h1, rowptr, cw, dinv, b1p, hbuf, N);

    // ---- layer 2 ----
    k_agg<0><<<nBlkAgg, 256, 0, stream>>>(hbuf, rowptr, cw, dinv, nullptr, agg2, N);
    k_gemm2<<<nBlkGemm, 256, 0, stream>>>(agg2, Bp2h, Bp2l, out_mu, out_ls,
                                          bmu, bls, N);
}

// Round 10
// 259.475 us; speedup vs baseline: 2.7696x; 1.0691x over previous
//
#include <hip/hip_runtime.h>
#include <hip/hip_fp16.h>

// ---------------------------------------------------------------------------
// VariationalGCNEncoder: mu/logstd = GCNConv(relu(GCNConv(x)))
// N=100000, E=1600000, IN=256, HID=128, OUT=64
//
// R10: fix R9's register-starved GEMMs (VGPR=68 -> serialized loads,
//      gemm1 75us). __launch_bounds__(256,3) lifts the VGPR cap to ~170;
//      A-chunk loads double-buffered (prefetch c+1 before computing c).
//      Rest identical to R9 (agg at its 66us random-row floor).
// Pipeline: memset -> bhist -> bpart -> bfin | prep_all | gemm1 -> agg<1>
//           -> agg<0> -> gemm2
// ---------------------------------------------------------------------------

typedef unsigned short ushort;
typedef __attribute__((ext_vector_type(8))) short bf16x8;
typedef __attribute__((ext_vector_type(8))) _Float16 f16x8;
typedef __attribute__((ext_vector_type(4))) float f32x4;

union U16x8 { uint4 q; ushort u[8]; bf16x8 b; f16x8 h; __half2 hh[4]; };

#define NBUCK 391   // ceil(100000/256)
#define BH_CHUNK 4096
#define BP_CHUNK 2048

// ---------------- bucket histogram -----------------------------------------
__global__ __launch_bounds__(256) void k_bhist(const int* __restrict__ dst,
                                               int* __restrict__ bucketCnt, int E) {
    __shared__ int hist[NBUCK];
    const int t = threadIdx.x;
    const int base = blockIdx.x * BH_CHUNK;
    const int cnt = min(BH_CHUNK, E - base);
    for (int i = t; i < NBUCK; i += 256) hist[i] = 0;
    __syncthreads();
    for (int i = t; i < cnt; i += 256) atomicAdd(&hist[dst[base + i] >> 8], 1);
    __syncthreads();
    for (int i = t; i < NBUCK; i += 256)
        if (hist[i]) atomicAdd(&bucketCnt[i], hist[i]);
}

// ---------------- partition: LDS counting sort per 2048-edge chunk ---------
__global__ __launch_bounds__(256) void k_bpart(const int* __restrict__ src,
                                               const int* __restrict__ dst,
                                               const int* __restrict__ bucketCnt,
                                               int* __restrict__ cur0,
                                               unsigned* __restrict__ cwTmp, int E) {
    __shared__ unsigned words[BP_CHUNK];
    __shared__ ushort buck[BP_CHUNK];
    __shared__ unsigned sortedW[BP_CHUNK];
    __shared__ ushort buck2[BP_CHUNK];
    __shared__ int sc[512];
    __shared__ int gsc[512];
    __shared__ int rk[NBUCK];
    __shared__ int runBase[NBUCK];
    const int t = threadIdx.x;
    const int base = blockIdx.x * BP_CHUNK;
    const int cnt = min(BP_CHUNK, E - base);

    // phase 0: local inclusive scan of global bucket counts
    gsc[t] = (t < NBUCK) ? bucketCnt[t] : 0;
    gsc[t + 256] = (t + 256 < NBUCK) ? bucketCnt[t + 256] : 0;
    sc[t] = 0; sc[t + 256] = 0;
    for (int i = t; i < NBUCK; i += 256) rk[i] = 0;
    __syncthreads();
    for (int off = 1; off < 512; off <<= 1) {
        int a0 = (t >= off) ? gsc[t - off] : 0;
        int a1 = (t + 256 >= off) ? gsc[t + 256 - off] : 0;
        __syncthreads();
        gsc[t] += a0;
        gsc[t + 256] += a1;
        __syncthreads();
    }
    // phase 1: load + per-chunk histogram
    for (int i = t; i < cnt; i += 256) {
        int s = src[base + i], d = dst[base + i];
        words[i] = ((unsigned)s << 8) | (unsigned)(d & 255);
        int b = d >> 8;
        buck[i] = (ushort)b;
        atomicAdd(&sc[b], 1);
    }
    __syncthreads();
    for (int off = 1; off < 512; off <<= 1) {
        int a0 = (t >= off) ? sc[t - off] : 0;
        int a1 = (t + 256 >= off) ? sc[t + 256 - off] : 0;
        __syncthreads();
        sc[t] += a0;
        sc[t + 256] += a1;
        __syncthreads();
    }
    // phase 2: scatter into bucket-sorted LDS order
    for (int i = t; i < cnt; i += 256) {
        int b = buck[i];
        int excl = b ? sc[b - 1] : 0;
        int p = excl + atomicAdd(&rk[b], 1);
        sortedW[p] = words[i];
        buck2[p] = (ushort)b;
    }
    __syncthreads();
    // phase 3: reserve global runs (one atomic per non-empty bucket)
    for (int b = t; b < NBUCK; b += 256) {
        int len = rk[b];
        if (len > 0) {
            int gbase = b ? gsc[b - 1] : 0;
            runBase[b] = gbase + atomicAdd(&cur0[b], len);
        }
    }
    __syncthreads();
    // phase 4: coalesced write-out of sorted runs
    for (int i = t; i < cnt; i += 256) {
        int b = buck2[i];
        int excl = b ? sc[b - 1] : 0;
        cwTmp[runBase[b] + (i - excl)] = sortedW[i];
    }
}

// ---------------- finalize: per-bucket node sort -> rowptr, dinv, cw -------
__global__ __launch_bounds__(256) void k_bfin(const unsigned* __restrict__ cwTmp,
                                              const int* __restrict__ bucketCnt,
                                              int* __restrict__ cw,
                                              int* __restrict__ rowptr,
                                              float* __restrict__ dinv,
                                              int N, int E) {
    __shared__ int hist[256], sc2[256], rk[256];
    __shared__ int gsc[512];
    const int b = blockIdx.x, t = threadIdx.x;
    gsc[t] = (t < NBUCK) ? bucketCnt[t] : 0;
    gsc[t + 256] = (t + 256 < NBUCK) ? bucketCnt[t + 256] : 0;
    hist[t] = 0;
    rk[t] = 0;
    __syncthreads();
    for (int off = 1; off < 512; off <<= 1) {
        int a0 = (t >= off) ? gsc[t - off] : 0;
        int a1 = (t + 256 >= off) ? gsc[t + 256 - off] : 0;
        __syncthreads();
        gsc[t] += a0;
        gsc[t + 256] += a1;
        __syncthreads();
    }
    const int gbase = b ? gsc[b - 1] : 0;
    const int gend = gsc[b];
    const int n0 = b << 8;
    const int nNodes = min(256, N - n0);
    for (int i = gbase + t; i < gend; i += 256)
        atomicAdd(&hist[cwTmp[i] & 255u], 1);
    __syncthreads();
    sc2[t] = hist[t];
    __syncthreads();
    for (int off = 1; off < 256; off <<= 1) {
        int a = (t >= off) ? sc2[t - off] : 0;
        __syncthreads();
        sc2[t] += a;
        __syncthreads();
    }
    int ex = sc2[t] - hist[t];  // exclusive
    if (t < nNodes) {
        rowptr[n0 + t] = gbase + ex;
        dinv[n0 + t] = rsqrtf((float)hist[t] + 1.0f);  // +1 self-loop
    }
    if (b == 0 && t == 0) rowptr[N] = E;
    __syncthreads();
    for (int i = gbase + t; i < gend; i += 256) {
        unsigned w = cwTmp[i];
        int dL = w & 255u;
        int r = atomicAdd(&rk[dL], 1);
        cw[gbase + (sc2[dL] - hist[dL]) + r] = (int)(w >> 8);
    }
}

// ---------------- merged weight pre-pack (25 blocks) -----------------------
__global__ __launch_bounds__(256) void k_prep_all(
    const float* __restrict__ W1, const float* __restrict__ Wmu,
    const float* __restrict__ Wls, const float* __restrict__ b1,
    ushort* __restrict__ B1h, ushort* __restrict__ B1l,
    ushort* __restrict__ B2h, ushort* __restrict__ B2l,
    float* __restrict__ b1p) {
    const int b = blockIdx.x, t = threadIdx.x;
    if (b < 16) {
        int i = b * 256 + t;  // 32*128 entries
        int kgrp = i >> 7, col = i & 127;
        U16x8 h, l;
#pragma unroll
        for (int j = 0; j < 8; ++j) {
            float x = W1[(size_t)(kgrp * 8 + j) * 128 + col];
            __half hh = __float2half(x);
            __half ll = __float2half(x - __half2float(hh));
            h.u[j] = __half_as_ushort(hh);
            l.u[j] = __half_as_ushort(ll);
        }
        *(uint4*)(B1h + (size_t)i * 8) = h.q;
        *(uint4*)(B1l + (size_t)i * 8) = l.q;
    } else if (b < 24) {
        int i = (b - 16) * 256 + t;  // 16*128 entries
        int kgrp = i >> 7, col = i & 127;
        U16x8 h, l;
#pragma unroll
        for (int j = 0; j < 8; ++j) {
            int lk = j * 16 + kgrp;  // stored_k -> logical hidden index
            float x = (col < 64) ? Wmu[(size_t)lk * 64 + col]
                                 : Wls[(size_t)lk * 64 + col - 64];
            __half hh = __float2half(x);
            __half ll = __float2half(x - __half2float(hh));
            h.u[j] = __half_as_ushort(hh);
            l.u[j] = __half_as_ushort(ll);
        }
        *(uint4*)(B2h + (size_t)i * 8) = h.q;
        *(uint4*)(B2l + (size_t)i * 8) = l.q;
    } else {
        if (t < 128) b1p[t] = b1[(t & 7) * 16 + (t >> 3)];
    }
}

// ---------------- GEMM1: h1' = dinv * (x @ W1), fp16 stored-order ----------
// A = f16(x); B = f16 hi/lo (2 MFMAs). Double-buffered A prefetch;
// launch_bounds(256,3) => VGPR cap ~170 so loads stay in flight.
__global__ __launch_bounds__(256, 3) void k_gemm1(const float* __restrict__ A,
                                                  const ushort* __restrict__ Bph,
                                                  const ushort* __restrict__ Bpl,
                                                  const float* __restrict__ dinv,
                                                  __half* __restrict__ H1, int M) {
    const int t = threadIdx.x, lane = t & 63;
    const int kgrp = lane >> 4, lrow = lane & 15;
    const int rowBase = blockIdx.x * 128 + (t >> 6) * 32;

    int r0 = rowBase + lrow;      if (r0 >= M) r0 = M - 1;
    int r1 = rowBase + 16 + lrow; if (r1 >= M) r1 = M - 1;
    const float* ap0 = A + (size_t)r0 * 256 + kgrp * 8;
    const float* ap1 = A + (size_t)r1 * 256 + kgrp * 8;

    f32x4 acc[2][8];
#pragma unroll
    for (int mf = 0; mf < 2; ++mf)
#pragma unroll
        for (int nf = 0; nf < 8; ++nf) acc[mf][nf] = (f32x4)0.f;

    float4 pa[2][2][2];  // [buf][mf][half] -- static after full unroll
    pa[0][0][0] = *(const float4*)ap0;
    pa[0][0][1] = *(const float4*)(ap0 + 4);
    pa[0][1][0] = *(const float4*)ap1;
    pa[0][1][1] = *(const float4*)(ap1 + 4);

#pragma unroll
    for (int c = 0; c < 8; ++c) {  // K=256
        const int cur = c & 1, nxt = cur ^ 1;
        if (c < 7) {  // prefetch next A chunk while computing this one
            const float* q0 = ap0 + (c + 1) * 32;
            const float* q1 = ap1 + (c + 1) * 32;
            pa[nxt][0][0] = *(const float4*)q0;
            pa[nxt][0][1] = *(const float4*)(q0 + 4);
            pa[nxt][1][0] = *(const float4*)q1;
            pa[nxt][1][1] = *(const float4*)(q1 + 4);
        }
        f16x8 ah[2];
#pragma unroll
        for (int mf = 0; mf < 2; ++mf) {
            float v[8];
            *(float4*)&v[0] = pa[cur][mf][0];
            *(float4*)&v[4] = pa[cur][mf][1];
            U16x8 h;
#pragma unroll
            for (int i = 0; i < 8; ++i)
                h.u[i] = __half_as_ushort(__float2half(v[i]));
            ah[mf] = h.h;
        }
#pragma unroll
        for (int nf = 0; nf < 8; ++nf) {
            size_t bo = ((size_t)(c * 4 + kgrp) * 128 + nf * 16 + lrow) * 8;
            U16x8 bh, bl;
            bh.q = *(const uint4*)(Bph + bo);
            bl.q = *(const uint4*)(Bpl + bo);
#pragma unroll
            for (int mf = 0; mf < 2; ++mf) {
                acc[mf][nf] = __builtin_amdgcn_mfma_f32_16x16x32_f16(
                    ah[mf], bh.h, acc[mf][nf], 0, 0, 0);
                acc[mf][nf] = __builtin_amdgcn_mfma_f32_16x16x32_f16(
                    ah[mf], bl.h, acc[mf][nf], 0, 0, 0);
            }
        }
    }
#pragma unroll
    for (int mf = 0; mf < 2; ++mf)
#pragma unroll
        for (int reg = 0; reg < 4; ++reg) {
            int row = rowBase + mf * 16 + kgrp * 4 + reg;
            if (row < M) {
                float dv = dinv[row];
                union { uint4 q; __half h[8]; } o;
#pragma unroll
                for (int nf = 0; nf < 8; ++nf)
                    o.h[nf] = __float2half(acc[mf][nf][reg] * dv);
                *(uint4*)(H1 + (size_t)row * 128 + lrow * 8) = o.q;
            }
        }
}

// ---------------- CSR gather (pure adds; rows pre-scaled) ------------------
template <int EPI>
__global__ __launch_bounds__(256) void k_agg(const __half* __restrict__ Hin,
                                             const int* __restrict__ rowptr,
                                             const int* __restrict__ cw,
                                             const float* __restrict__ dinv,
                                             const float* __restrict__ b1p,
                                             __half* __restrict__ Hout, int N) {
    int node = (blockIdx.x * 256 + threadIdx.x) >> 6;
    int lane = threadIdx.x & 63;
    if (node >= N) return;
    float2 acc = __half22float2(((const __half2*)(Hin + (size_t)node * 128))[lane]);
    int e = rowptr[node], end = rowptr[node + 1];
    for (; e + 8 <= end; e += 8) {
        int s0 = cw[e], s1 = cw[e + 1], s2 = cw[e + 2], s3 = cw[e + 3];
        int s4 = cw[e + 4], s5 = cw[e + 5], s6 = cw[e + 6], s7 = cw[e + 7];
        float2 f0 = __half22float2(((const __half2*)(Hin + (size_t)s0 * 128))[lane]);
        float2 f1 = __half22float2(((const __half2*)(Hin + (size_t)s1 * 128))[lane]);
        float2 f2 = __half22float2(((const __half2*)(Hin + (size_t)s2 * 128))[lane]);
        float2 f3 = __half22float2(((const __half2*)(Hin + (size_t)s3 * 128))[lane]);
        float2 f4 = __half22float2(((const __half2*)(Hin + (size_t)s4 * 128))[lane]);
        float2 f5 = __half22float2(((const __half2*)(Hin + (size_t)s5 * 128))[lane]);
        float2 f6 = __half22float2(((const __half2*)(Hin + (size_t)s6 * 128))[lane]);
        float2 f7 = __half22float2(((const __half2*)(Hin + (size_t)s7 * 128))[lane]);
        acc.x += f0.x; acc.y += f0.y; acc.x += f1.x; acc.y += f1.y;
        acc.x += f2.x; acc.y += f2.y; acc.x += f3.x; acc.y += f3.y;
        acc.x += f4.x; acc.y += f4.y; acc.x += f5.x; acc.y += f5.y;
        acc.x += f6.x; acc.y += f6.y; acc.x += f7.x; acc.y += f7.y;
    }
    for (; e + 2 <= end; e += 2) {
        int s0 = cw[e], s1 = cw[e + 1];
        float2 f0 = __half22float2(((const __half2*)(Hin + (size_t)s0 * 128))[lane]);
        float2 f1 = __half22float2(((const __half2*)(Hin + (size_t)s1 * 128))[lane]);
        acc.x += f0.x; acc.y += f0.y; acc.x += f1.x; acc.y += f1.y;
    }
    if (e < end) {
        int s0 = cw[e];
        float2 f0 = __half22float2(((const __half2*)(Hin + (size_t)s0 * 128))[lane]);
        acc.x += f0.x; acc.y += f0.y;
    }
    float dv = dinv[node];
    if (EPI == 1) {
        float2 bb = ((const float2*)b1p)[lane];
        acc.x = fmaxf(fmaf(acc.x, dv, bb.x), 0.f) * dv;
        acc.y = fmaxf(fmaf(acc.y, dv, bb.y), 0.f) * dv;
    } else {
        acc.x *= dv;
        acc.y *= dv;
    }
    ((__half2*)(Hout + (size_t)node * 128))[lane] = __float22half2_rn(acc);
}

// ---------------- GEMM2: [mu|ls] = agg2 @ [Wmu|Wls] + bias -----------------
// Same pipelined-prefetch treatment as GEMM1.
__global__ __launch_bounds__(256, 3) void k_gemm2(const __half* __restrict__ A,
                                                  const ushort* __restrict__ Bph,
                                                  const ushort* __restrict__ Bpl,
                                                  float* __restrict__ Cmu,
                                                  float* __restrict__ Cls,
                                                  const float* __restrict__ bmu,
                                                  const float* __restrict__ bls,
                                                  int M) {
    const int t = threadIdx.x, lane = t & 63;
    const int kgrp = lane >> 4, lrow = lane & 15;
    const int rowBase = blockIdx.x * 128 + (t >> 6) * 32;

    int r0 = rowBase + lrow;      if (r0 >= M) r0 = M - 1;
    int r1 = rowBase + 16 + lrow; if (r1 >= M) r1 = M - 1;
    const __half* ap0 = A + (size_t)r0 * 128 + kgrp * 8;
    const __half* ap1 = A + (size_t)r1 * 128 + kgrp * 8;

    f32x4 acc[2][8];
#pragma unroll
    for (int mf = 0; mf < 2; ++mf)
#pragma unroll
        for (int nf = 0; nf < 8; ++nf) acc[mf][nf] = (f32x4)0.f;

    uint4 pa[2][2];  // [buf][mf]
    pa[0][0] = *(const uint4*)ap0;
    pa[0][1] = *(const uint4*)ap1;

#pragma unroll
    for (int c = 0; c < 4; ++c) {  // K=128 stored
        const int cur = c & 1, nxt = cur ^ 1;
        if (c < 3) {
            pa[nxt][0] = *(const uint4*)(ap0 + (c + 1) * 32);
            pa[nxt][1] = *(const uint4*)(ap1 + (c + 1) * 32);
        }
        f16x8 a[2];
#pragma unroll
        for (int mf = 0; mf < 2; ++mf) {
            U16x8 u;
            u.q = pa[cur][mf];
            a[mf] = u.h;
        }
#pragma unroll
        for (int nf = 0; nf < 8; ++nf) {
            size_t bo = ((size_t)(c * 4 + kgrp) * 128 + nf * 16 + lrow) * 8;
            U16x8 bh, bl;
            bh.q = *(const uint4*)(Bph + bo);
            bl.q = *(const uint4*)(Bpl + bo);
#pragma unroll
            for (int mf = 0; mf < 2; ++mf) {
                acc[mf][nf] = __builtin_amdgcn_mfma_f32_16x16x32_f16(
                    a[mf], bh.h, acc[mf][nf], 0, 0, 0);
                acc[mf][nf] = __builtin_amdgcn_mfma_f32_16x16x32_f16(
                    a[mf], bl.h, acc[mf][nf], 0, 0, 0);
            }
        }
    }
    float bv[8];
#pragma unroll
    for (int nf = 0; nf < 8; ++nf)
        bv[nf] = (nf < 4) ? bmu[nf * 16 + lrow] : bls[(nf - 4) * 16 + lrow];
#pragma unroll
    for (int mf = 0; mf < 2; ++mf)
#pragma unroll
        for (int reg = 0; reg < 4; ++reg) {
            int row = rowBase + mf * 16 + kgrp * 4 + reg;
            if (row < M) {
#pragma unroll
                for (int nf = 0; nf < 4; ++nf)
                    __builtin_nontemporal_store(
                        acc[mf][nf][reg] + bv[nf],
                        &Cmu[(size_t)row * 64 + nf * 16 + lrow]);
#pragma unroll
                for (int nf = 4; nf < 8; ++nf)
                    __builtin_nontemporal_store(
                        acc[mf][nf][reg] + bv[nf],
                        &Cls[(size_t)row * 64 + (nf - 4) * 16 + lrow]);
            }
        }
}

extern "C" void kernel_launch(void* const* d_in, const int* in_sizes, int n_in,
                              void* d_out, int out_size, void* d_ws, size_t ws_size,
                              hipStream_t stream) {
    const float* x   = (const float*)d_in[0];
    const int*   ei  = (const int*)d_in[1];
    const float* W1  = (const float*)d_in[2];
    const float* b1  = (const float*)d_in[3];
    const float* Wmu = (const float*)d_in[4];
    const float* bmu = (const float*)d_in[5];
    const float* Wls = (const float*)d_in[6];
    const float* bls = (const float*)d_in[7];

    const int N = in_sizes[0] / 256;  // 100000
    const int E = in_sizes[1] / 2;    // 1600000
    const int* src = ei;
    const int* dst = ei + E;

    float* out_mu = (float*)d_out;
    float* out_ls = out_mu + (size_t)N * 64;

    // ---- workspace layout ----
    char* wsb = (char*)d_ws;
    const size_t KB = 1024, MB = 1024 * 1024;
    const size_t Hh_BYTES = (size_t)N * 128 * 2;  // 25.6 MB
    int*      bucketCnt = (int*)(wsb + 0);           // 392 ints
    int*      cur0      = (int*)(wsb + 2 * KB);      // 392 ints (zeroed)
    float*    b1p       = (float*)(wsb + 16 * KB);
    ushort*   Bp1h      = (ushort*)(wsb + 32 * KB);  // 64 KB
    ushort*   Bp1l      = (ushort*)(wsb + 96 * KB);  // 64 KB
    ushort*   Bp2h      = (ushort*)(wsb + 160 * KB); // 32 KB
    ushort*   Bp2l      = (ushort*)(wsb + 192 * KB); // 32 KB
    int*      rowptr    = (int*)(wsb + 256 * KB);
    float*    dinv      = (float*)(wsb + 768 * KB);
    unsigned* cwTmp     = (unsigned*)(wsb + 1280 * KB);  // 6.4 MB
    int*      cw        = (int*)(wsb + 8 * MB);          // 6.4 MB
    __half*   h1        = (__half*)(wsb + 15 * MB);      // 25.6 MB
    __half*   hbuf;                                      // h'
    __half*   agg2;
    if (ws_size >= 67 * MB + Hh_BYTES) {
        hbuf = (__half*)(wsb + 41 * MB);
        agg2 = (__half*)(wsb + 67 * MB);
    } else {
        hbuf = (__half*)d_out;  // 25.6 <= 51.2 MB; d_out rewritten by GEMM2
        agg2 = (__half*)(wsb + 41 * MB);
    }

    const int nChunksH = (E + BH_CHUNK - 1) / BH_CHUNK;  // 391
    const int nChunksP = (E + BP_CHUNK - 1) / BP_CHUNK;  // 782
    const int nBlkAgg  = (N + 3) / 4;
    const int nBlkGemm = (N + 127) / 128;

    // ---- CSR build (bucketed counting sort) ----
    hipMemsetAsync(wsb, 0, 4 * KB, stream);  // bucketCnt + cur0
    k_bhist<<<nChunksH, 256, 0, stream>>>(dst, bucketCnt, E);
    k_bpart<<<nChunksP, 256, 0, stream>>>(src, dst, bucketCnt, cur0, cwTmp, E);
    k_bfin<<<NBUCK, 256, 0, stream>>>(cwTmp, bucketCnt, cw, rowptr, dinv, N, E);

    // ---- weight prepacks (single launch) ----
    k_prep_all<<<25, 256, 0, stream>>>(W1, Wmu, Wls, b1, Bp1h, Bp1l, Bp2h, Bp2l, b1p);

    // ---- layer 1 ----
    k_gemm1<<<nBlkGemm, 256, 0, stream>>>(x, Bp1h, Bp1l, dinv, h1, N);
    k_agg<1><<<nBlkAgg, 256, 0, stream>>>(h1, rowptr, cw, dinv, b1p, hbuf, N);

    // ---- layer 2 ----
    k_agg<0><<<nBlkAgg, 256, 0, stream>>>(hbuf, rowptr, cw, dinv, nullptr, agg2, N);
    k_gemm2<<<nBlkGemm, 256, 0, stream>>>(agg2, Bp2h, Bp2l, out_mu, out_ls,
                                          bmu, bls, N);
}